// Round 2
// baseline (130.612 us; speedup 1.0000x reference)
//
#include <hip/hip_runtime.h>
#include <math.h>

// GaussianCircular: separable 15x15 Gaussian conv, fp32, SAME zero-pad.
// R7: R5's streaming ring + PREFETCH DEPTH D across RAW BARRIERS.
//   R5 post-mortem: __syncthreads() forces `s_waitcnt vmcnt(0)` before every
//   s_barrier -> 1 load in flight per wave -> 10 KB/CU outstanding, vs the
//   ~22 KB (900cy x 24.6 B/cy) needed to saturate HBM -> 2.9 TB/s observed.
//   R6 post-mortem: batch-30-loads + 66KB LDS: allocator refused 30 live
//   float4 dests (VGPR=100, serialized) AND occupancy fell to 2 blocks/CU.
// Fix here (HK T4, plain HIP): ring of 15+D input rows; load row k+7+D at
// iter k (consumed D iters later -> compiler emits vmcnt(D), not 0), and use
// raw __builtin_amdgcn_s_barrier() with an explicit lgkmcnt(0)-only drain so
// global loads stay in flight ACROSS the per-row barriers. LDS stays tiny
// (2 x 1040 words) so occupancy stays high: ~12 waves/CU x 6 KB = 72 KB in
// flight per CU >> 22 KB -> HBM-bound for real.

#define RAD   7
#define KS    15
#define S     16               // output rows per strip
#define PRE   (2 * RAD)        // 14 prologue rows
#define D     6                // prefetch depth (loads in flight per wave)
#define RINGN (KS + D)         // 21 ring slots
#define NIN   (S + PRE)        // 30 input rows per strip
#define PADW  8                // zero pad words each side of mid row
#define MIDW  (1024 + 2 * PADW)

using f32x4 = __attribute__((ext_vector_type(4))) float;

__global__ __launch_bounds__(256) void gauss_ring_pf_kernel(
    const float* __restrict__ x,
    const float* __restrict__ sigma_p,
    const float* __restrict__ gain_p,
    float* __restrict__ out,
    int H, int W)
{
    __shared__ float smid[2][MIDW];          // 2 x 1040 fp32 = 8320 B

    const int strips = H / S;                // 64
    const int n      = blockIdx.x / strips;
    const int strip  = blockIdx.x - n * strips;
    const int row0   = strip * S;

    const int tid = threadIdx.x;
    const int c0  = tid * 4;                 // 256 thr * 4 = 1024 = W

    const float* __restrict__ img    = x   + (size_t)n * H * W;
    float*       __restrict__ outimg = out + (size_t)n * H * W;

    // Separable weights: gain*exp(-(i^2+j^2)/2s^2) = gain * w[i] * w[j]
    const float s    = fabsf(sigma_p[0]);
    const float gain = gain_p[0];
    const float inv  = -1.0f / (2.0f * s * s);
    float w[KS];
#pragma unroll
    for (int j = 0; j < KS; ++j) {
        const float d = (float)(j - RAD);
        w[j] = expf(d * d * inv);
    }

    // Zero the pads once (read every row, never rewritten; first read is
    // after the k=0 barrier whose lgkmcnt(0) drain makes these visible).
    if (tid < PADW) {
        smid[0][tid] = 0.0f;
        smid[1][tid] = 0.0f;
        smid[0][PADW + 1024 + tid] = 0.0f;
        smid[1][PADW + 1024 + tid] = 0.0f;
    }

    // ---- prologue: input rows row0-7 .. row0+6+D -> ring slots 0..13+D ----
    // (gr <= row0+RAD+D-1 <= 1020 < H always, so only the lower clamp/mask)
    float4 ring[RINGN];
#pragma unroll
    for (int p = 0; p < PRE + D; ++p) {
        const int gr  = row0 - RAD + p;
        const int grc = max(gr, 0);
        const float m = (gr >= 0) ? 1.0f : 0.0f;
        float4 v = *(const float4*)(img + (size_t)grc * W + c0);
        v.x *= m; v.y *= m; v.z *= m; v.w *= m;
        ring[p] = v;
    }

    // ---- main: 16 output rows, one barrier per row, vmcnt never drained ----
#pragma unroll
    for (int k = 0; k < S; ++k) {
        // prefetch input row row0+k+RAD+D -> slot (k+PRE+D)%RINGN.
        // Consumed at iter k+D, so D loads stay outstanding per wave.
        // Compile-time guard: last D iterations have nothing left to load
        // (total loads per thread stays exactly NIN=30).
        if (k + PRE + D < NIN) {
            const int p   = k + PRE + D;
            const int gr  = row0 - RAD + p;          // = row0 + k + RAD + D
            const int grc = min(gr, H - 1);          // only upper clamp here
            const float m = (gr < H) ? 1.0f : 0.0f;
            float4 v = *(const float4*)(img + (size_t)grc * W + c0);
            v.x *= m; v.y *= m; v.z *= m; v.w *= m;
            ring[p % RINGN] = v;
        }

        // vertical pass: mid row o = row0+k from ring rows o-7..o+7
        float4 mid = make_float4(0.f, 0.f, 0.f, 0.f);
#pragma unroll
        for (int i = 0; i < KS; ++i) {
            const float wv  = w[i];
            const float4 r  = ring[(k + i) % RINGN]; // static after unroll
            mid.x += wv * r.x; mid.y += wv * r.y;
            mid.z += wv * r.z; mid.w += wv * r.w;
        }

        const int buf = k & 1;
        *(float4*)&smid[buf][PADW + c0] = mid;

        // RAW barrier: drain LDS ops only (producer/consumer correctness);
        // global prefetch loads stay in flight across the barrier (the point).
        asm volatile("s_waitcnt lgkmcnt(0)" ::: "memory");
        __builtin_amdgcn_s_barrier();
        asm volatile("" ::: "memory");   // compiler fence: no LDS-read hoist

        // horizontal pass: 5 aligned b128 LDS reads -> window [c0-8, c0+12)
        const float* mp = &smid[buf][c0];            // word c0 = PADW+c0-8
        const float4 f0 = *(const float4*)(mp);
        const float4 f1 = *(const float4*)(mp + 4);
        const float4 f2 = *(const float4*)(mp + 8);
        const float4 f3 = *(const float4*)(mp + 12);
        const float4 f4 = *(const float4*)(mp + 16);
        float f[20] = { f0.x, f0.y, f0.z, f0.w,
                        f1.x, f1.y, f1.z, f1.w,
                        f2.x, f2.y, f2.z, f2.w,
                        f3.x, f3.y, f3.z, f3.w,
                        f4.x, f4.y, f4.z, f4.w };
        float4 acc = make_float4(0.f, 0.f, 0.f, 0.f);
#pragma unroll
        for (int jj = 0; jj < KS; ++jj) {
            const float wv = w[jj];
            acc.x += wv * f[1 + jj];
            acc.y += wv * f[2 + jj];
            acc.z += wv * f[3 + jj];
            acc.w += wv * f[4 + jj];
        }
        acc.x *= gain; acc.y *= gain; acc.z *= gain; acc.w *= gain;

        float* op = outimg + (size_t)(row0 + k) * W + c0;
        __builtin_nontemporal_store(*(const f32x4*)&acc, (f32x4*)op);
    }
}

extern "C" void kernel_launch(void* const* d_in, const int* in_sizes, int n_in,
                              void* d_out, int out_size, void* d_ws, size_t ws_size,
                              hipStream_t stream) {
    const float* x       = (const float*)d_in[0];
    const float* sigma_p = (const float*)d_in[1];
    const float* gain_p  = (const float*)d_in[2];
    float* out = (float*)d_out;

    const int H = 1024, W = 1024;
    const int N = in_sizes[0] / (H * W);               // 16

    const dim3 grid(N * (H / S));                      // 16 * 64 = 1024 blocks
    gauss_ring_pf_kernel<<<grid, 256, 0, stream>>>(x, sigma_p, gain_p, out, H, W);
}

// Round 3
// 127.456 us; speedup vs baseline: 1.0248x; 1.0248x over previous
//
#include <hip/hip_runtime.h>
#include <math.h>

// GaussianCircular: separable 15x15 Gaussian conv, fp32, SAME zero-pad.
// R8 = R7 + XCD-chunked blockIdx swizzle.
//   R7 (verified, dispatch dropped below the 42us harness fills): streaming
//   ring of 15+D input rows, prefetch depth D=6 held in flight ACROSS raw
//   barriers (lgkmcnt(0)-only drain + __builtin_amdgcn_s_barrier), so vmcnt
//   is never forced to 0 in the main loop. Traffic already compulsory-minimal
//   (FETCH 61MB ~= input, WRITE 64MB exact -> 20us floor @ 6.3TB/s).
//   R8: adjacent strips share a 14-row (57KB) halo. Default block->XCD
//   round-robin puts consecutive strips on DIFFERENT XCDs -> halo re-reads
//   served by die-level L3. Bijective chunked swizzle (1024 blocks % 8 == 0)
//   gives each XCD contiguous strip ranges -> halos hit the local 4MB L2.
//   Keep R5's lesson: loads stay UNCONDITIONAL (clamped row + 0/1 mask) so
//   the compiler can batch/pipeline them; do NOT branch around loads.

#define RAD   7
#define KS    15
#define S     16               // output rows per strip
#define PRE   (2 * RAD)        // 14 prologue rows
#define D     6                // prefetch depth (loads in flight per wave)
#define RINGN (KS + D)         // 21 ring slots
#define NIN   (S + PRE)        // 30 input rows per strip
#define PADW  8                // zero pad words each side of mid row
#define MIDW  (1024 + 2 * PADW)
#define NXCD  8

using f32x4 = __attribute__((ext_vector_type(4))) float;

__global__ __launch_bounds__(256) void gauss_ring_xcd_kernel(
    const float* __restrict__ x,
    const float* __restrict__ sigma_p,
    const float* __restrict__ gain_p,
    float* __restrict__ out,
    int H, int W)
{
    __shared__ float smid[2][MIDW];          // 2 x 1040 fp32 = 8320 B

    // --- bijective XCD-chunked swizzle (nwg = 1024, 1024 % 8 == 0) ---
    // HW round-robins blockIdx.x % 8 across XCDs; remap so XCD k processes
    // a contiguous range of work ids -> adjacent strips co-located on one
    // XCD's L2, and bid/bid+8 (the same XCD's next strip) launch adjacently.
    const int nwg  = gridDim.x;
    const int cpx  = nwg / NXCD;             // 128
    const int bid  = blockIdx.x;
    const int wid  = (bid & (NXCD - 1)) * cpx + (bid >> 3);

    const int strips = H / S;                // 64
    const int n      = wid / strips;
    const int strip  = wid - n * strips;
    const int row0   = strip * S;

    const int tid = threadIdx.x;
    const int c0  = tid * 4;                 // 256 thr * 4 = 1024 = W

    const float* __restrict__ img    = x   + (size_t)n * H * W;
    float*       __restrict__ outimg = out + (size_t)n * H * W;

    // Separable weights: gain*exp(-(i^2+j^2)/2s^2) = gain * w[i] * w[j]
    const float s    = fabsf(sigma_p[0]);
    const float gain = gain_p[0];
    const float inv  = -1.0f / (2.0f * s * s);
    float w[KS];
#pragma unroll
    for (int j = 0; j < KS; ++j) {
        const float d = (float)(j - RAD);
        w[j] = expf(d * d * inv);
    }

    // Zero the pads once (read every row, never rewritten; first read is
    // after the k=0 barrier whose lgkmcnt(0) drain makes these visible).
    if (tid < PADW) {
        smid[0][tid] = 0.0f;
        smid[1][tid] = 0.0f;
        smid[0][PADW + 1024 + tid] = 0.0f;
        smid[1][PADW + 1024 + tid] = 0.0f;
    }

    // ---- prologue: input rows row0-7 .. row0+6+D -> ring slots 0..13+D ----
    // (gr <= row0+RAD+D-1 <= 1020 < H always, so only the lower clamp/mask)
    float4 ring[RINGN];
#pragma unroll
    for (int p = 0; p < PRE + D; ++p) {
        const int gr  = row0 - RAD + p;
        const int grc = max(gr, 0);
        const float m = (gr >= 0) ? 1.0f : 0.0f;
        float4 v = *(const float4*)(img + (size_t)grc * W + c0);
        v.x *= m; v.y *= m; v.z *= m; v.w *= m;
        ring[p] = v;
    }

    // ---- main: 16 output rows, one barrier per row, vmcnt never drained ----
#pragma unroll
    for (int k = 0; k < S; ++k) {
        // prefetch input row row0+k+RAD+D -> slot (k+PRE+D)%RINGN.
        // Consumed at iter k+D, so D loads stay outstanding per wave.
        // Compile-time guard: last D iterations have nothing left to load
        // (total loads per thread stays exactly NIN=30).
        if (k + PRE + D < NIN) {
            const int p   = k + PRE + D;
            const int gr  = row0 - RAD + p;          // = row0 + k + RAD + D
            const int grc = min(gr, H - 1);          // only upper clamp here
            const float m = (gr < H) ? 1.0f : 0.0f;
            float4 v = *(const float4*)(img + (size_t)grc * W + c0);
            v.x *= m; v.y *= m; v.z *= m; v.w *= m;
            ring[p % RINGN] = v;
        }

        // vertical pass: mid row o = row0+k from ring rows o-7..o+7
        float4 mid = make_float4(0.f, 0.f, 0.f, 0.f);
#pragma unroll
        for (int i = 0; i < KS; ++i) {
            const float wv  = w[i];
            const float4 r  = ring[(k + i) % RINGN]; // static after unroll
            mid.x += wv * r.x; mid.y += wv * r.y;
            mid.z += wv * r.z; mid.w += wv * r.w;
        }

        const int buf = k & 1;
        *(float4*)&smid[buf][PADW + c0] = mid;

        // RAW barrier: drain LDS ops only (producer/consumer correctness);
        // global prefetch loads stay in flight across the barrier (the point).
        asm volatile("s_waitcnt lgkmcnt(0)" ::: "memory");
        __builtin_amdgcn_s_barrier();
        asm volatile("" ::: "memory");   // compiler fence: no LDS-read hoist

        // horizontal pass: 5 aligned b128 LDS reads -> window [c0-8, c0+12)
        const float* mp = &smid[buf][c0];            // word c0 = PADW+c0-8
        const float4 f0 = *(const float4*)(mp);
        const float4 f1 = *(const float4*)(mp + 4);
        const float4 f2 = *(const float4*)(mp + 8);
        const float4 f3 = *(const float4*)(mp + 12);
        const float4 f4 = *(const float4*)(mp + 16);
        float f[20] = { f0.x, f0.y, f0.z, f0.w,
                        f1.x, f1.y, f1.z, f1.w,
                        f2.x, f2.y, f2.z, f2.w,
                        f3.x, f3.y, f3.z, f3.w,
                        f4.x, f4.y, f4.z, f4.w };
        float4 acc = make_float4(0.f, 0.f, 0.f, 0.f);
#pragma unroll
        for (int jj = 0; jj < KS; ++jj) {
            const float wv = w[jj];
            acc.x += wv * f[1 + jj];
            acc.y += wv * f[2 + jj];
            acc.z += wv * f[3 + jj];
            acc.w += wv * f[4 + jj];
        }
        acc.x *= gain; acc.y *= gain; acc.z *= gain; acc.w *= gain;

        float* op = outimg + (size_t)(row0 + k) * W + c0;
        __builtin_nontemporal_store(*(const f32x4*)&acc, (f32x4*)op);
    }
}

extern "C" void kernel_launch(void* const* d_in, const int* in_sizes, int n_in,
                              void* d_out, int out_size, void* d_ws, size_t ws_size,
                              hipStream_t stream) {
    const float* x       = (const float*)d_in[0];
    const float* sigma_p = (const float*)d_in[1];
    const float* gain_p  = (const float*)d_in[2];
    float* out = (float*)d_out;

    const int H = 1024, W = 1024;
    const int N = in_sizes[0] / (H * W);               // 16

    const dim3 grid(N * (H / S));                      // 16 * 64 = 1024 blocks
    gauss_ring_xcd_kernel<<<grid, 256, 0, stream>>>(x, sigma_p, gain_p, out, H, W);
}